// Round 2
// baseline (714.286 us; speedup 1.0000x reference)
//
#include <hip/hip_runtime.h>
#include <math.h>

#define RGRID 128
#define NSTEPS 128
#define DATA_DIM 28
#define NSEG 2
#define SEGSTEPS (NSTEPS / NSEG)

__device__ __forceinline__ float fast_rcp(float x) { return __builtin_amdgcn_rcpf(x); }

// 16 lanes per ray: lane = seg*8 + corner.
// corner c: dz=c&1, dy=(c>>1)&1, dx=(c>>2)&1 (adjacent lane pairs read contiguous 224B).
// Each 8-lane group renders one 64-step segment; segments combine via shfl_xor(8):
//   rgb = rgb_A + T_A*rgb_B, T = T_A*T_B  (compositing is associative).
__global__ __launch_bounds__(256) void render_kernel(
    const float* __restrict__ rays_o,
    const float* __restrict__ rays_d,
    const float* __restrict__ grid,
    const float* __restrict__ scaling,
    const float* __restrict__ offset,
    float* __restrict__ out, int N)
{
    int tid = blockIdx.x * blockDim.x + threadIdx.x;
    int ray = tid >> 4;
    int sub = tid & 15;
    int seg = sub >> 3;
    int corner = sub & 7;
    if (ray >= N) return;

    float ox = rays_o[ray * 3 + 0], oy = rays_o[ray * 3 + 1], oz = rays_o[ray * 3 + 2];
    float rdx = rays_d[ray * 3 + 0], rdy = rays_d[ray * 3 + 1], rdz = rays_d[ray * 3 + 2];
    float sx = scaling[0], sy = scaling[1], sz = scaling[2];
    float fx = offset[0], fy = offset[1], fz = offset[2];

    // normalize direction
    float dn = rsqrtf(rdx * rdx + rdy * rdy + rdz * rdz);
    float dirx = rdx * dn, diry = rdy * dn, dirz = rdz * dn;

    float o0 = ox * sx + fx, o1 = oy * sy + fy, o2 = oz * sz + fz;
    float d0 = dirx * sx, d1 = diry * sy, d2 = dirz * sz;
    float delta_scale = rsqrtf(d0 * d0 + d1 * d1 + d2 * d2);

    float a0 = fabsf(d0) > 1e-9f ? d0 : 1e-9f;
    float a1 = fabsf(d1) > 1e-9f ? d1 : 1e-9f;
    float a2 = fabsf(d2) > 1e-9f ? d2 : 1e-9f;
    float i0 = 1.0f / a0, i1 = 1.0f / a1, i2 = 1.0f / a2;

    float t1x = (0.0f - o0) * i0, t2x = (1.0f - o0) * i0;
    float t1y = (0.0f - o1) * i1, t2y = (1.0f - o1) * i1;
    float t1z = (0.0f - o2) * i2, t2z = (1.0f - o2) * i2;
    float tmin = fmaxf(fmaxf(fminf(t1x, t2x), fminf(t1y, t2y)), fminf(t1z, t2z));
    tmin = fmaxf(tmin, 0.0f);
    float tmax = fminf(fminf(fmaxf(t1x, t2x), fmaxf(t1y, t2y)), fmaxf(t1z, t2z));
    bool valid = tmax > tmin;
    float dt = valid ? (tmax - tmin) * (1.0f / NSTEPS) : 0.0f;
    float sig_scale = dt * delta_scale;

    // SH basis (degree 2, 9 terms)
    const float C0 = 0.28209479177387814f;
    const float C1 = 0.4886025119029199f;
    float b0 = C0;
    float b1 = -C1 * diry;
    float b2 = C1 * dirz;
    float b3 = -C1 * dirx;
    float b4 = 1.0925484305920792f * dirx * diry;
    float b5 = -1.0925484305920792f * diry * dirz;
    float b6 = 0.31539156525252005f * (2.0f * dirz * dirz - dirx * dirx - diry * diry);
    float b7 = -1.0925484305920792f * dirx * dirz;
    float b8 = 0.5462742152960396f * (dirx * dirx - diry * diry);

    int cdx = (corner >> 2) & 1, cdy = (corner >> 1) & 1, cdz = corner & 1;
    // per-lane constant voxel-index offset for this corner
    int laneoff = (cdx << 14) + (cdy << 7) + cdz;
    // FMA-form corner weights: w_c = fs*w + fb  (fs=+1,fb=0 if high corner; fs=-1,fb=1 if low)
    float fsx = cdx ? 1.0f : -1.0f, fbx = cdx ? 0.0f : 1.0f;
    float fsy = cdy ? 1.0f : -1.0f, fby = cdy ? 0.0f : 1.0f;
    float fsz = cdz ? 1.0f : -1.0f, fbz = cdz ? 0.0f : 1.0f;

    float T = 1.0f, accr = 0.0f, accg = 0.0f, accb = 0.0f;
    float tstart = tmin + ((float)(seg * SEGSTEPS) + 0.5f) * dt;

    #pragma unroll 2
    for (int i = 0; i < SEGSTEPS; i++) {
        float t = tstart + (float)i * dt;
        float px = o0 + t * d0, py = o1 + t * d1, pz = o2 + t * d2;

        float gx = px * (float)RGRID - 0.5f;
        float gy = py * (float)RGRID - 0.5f;
        float gz = pz * (float)RGRID - 0.5f;
        gx = fminf(fmaxf(gx, 0.0f), 126.9999f);
        gy = fminf(fmaxf(gy, 0.0f), 126.9999f);
        gz = fminf(fmaxf(gz, 0.0f), 126.9999f);

        float flx = floorf(gx), fly = floorf(gy), flz = floorf(gz);
        int ix = (int)flx, iy = (int)fly, iz = (int)flz;
        float wx = gx - flx, wy = gy - fly, wz = gz - flz;

        float wgt = (fsx * wx + fbx) * (fsy * wy + fby) * (fsz * wz + fbz);

        int vox = (ix << 14) + (iy << 7) + iz + laneoff;
        const float4* gp = (const float4*)(grid + (size_t)vox * DATA_DIM);
        float4 v0 = gp[0], v1 = gp[1], v2 = gp[2], v3 = gp[3], v4 = gp[4], v5 = gp[5], v6 = gp[6];

        // channels 0..8 -> red SH, 9..17 green, 18..26 blue, 27 sigma
        float vr = b0 * v0.x + b1 * v0.y + b2 * v0.z + b3 * v0.w
                 + b4 * v1.x + b5 * v1.y + b6 * v1.z + b7 * v1.w + b8 * v2.x;
        float vg = b0 * v2.y + b1 * v2.z + b2 * v2.w
                 + b3 * v3.x + b4 * v3.y + b5 * v3.z + b6 * v3.w
                 + b7 * v4.x + b8 * v4.y;
        float vb = b0 * v4.z + b1 * v4.w
                 + b2 * v5.x + b3 * v5.y + b4 * v5.z + b5 * v5.w
                 + b6 * v6.x + b7 * v6.y + b8 * v6.z;
        float vs = v6.w;

        vr *= wgt; vg *= wgt; vb *= wgt; vs *= wgt;

        // butterfly sum across the 8 corner lanes (stays inside the 8-lane group)
        #pragma unroll
        for (int m = 1; m < 8; m <<= 1) {
            vr += __shfl_xor(vr, m);
            vg += __shfl_xor(vg, m);
            vb += __shfl_xor(vb, m);
            vs += __shfl_xor(vs, m);
        }

        float sigma = valid ? fmaxf(vs, 0.0f) : 0.0f;
        float alpha = 1.0f - __expf(-sigma * sig_scale);
        float cr = fast_rcp(1.0f + __expf(-vr));
        float cg = fast_rcp(1.0f + __expf(-vg));
        float cb = fast_rcp(1.0f + __expf(-vb));
        float ta = T * alpha;
        accr += ta * cr;
        accg += ta * cg;
        accb += ta * cb;
        T -= ta;
    }

    // combine segments: seg0 lanes get seg1's state via xor(8)
    float oT = __shfl_xor(T, 8);
    float orr = __shfl_xor(accr, 8);
    float org = __shfl_xor(accg, 8);
    float orb = __shfl_xor(accb, 8);

    if (sub == 0) {
        float Tf = T * oT;
        out[ray * 3 + 0] = accr + T * orr + Tf * 1.0f;  // BG = 1.0
        out[ray * 3 + 1] = accg + T * org + Tf * 1.0f;
        out[ray * 3 + 2] = accb + T * orb + Tf * 1.0f;
    }
}

extern "C" void kernel_launch(void* const* d_in, const int* in_sizes, int n_in,
                              void* d_out, int out_size, void* d_ws, size_t ws_size,
                              hipStream_t stream) {
    const float* rays_o  = (const float*)d_in[0];
    const float* rays_d  = (const float*)d_in[1];
    const float* grid    = (const float*)d_in[2];
    const float* scaling = (const float*)d_in[3];
    const float* offset  = (const float*)d_in[4];
    float* out = (float*)d_out;
    int N = in_sizes[0] / 3;  // 32768 rays

    int threads = 256;
    int total = N * 16;  // 16 lanes per ray (8 corners x 2 segments)
    int blocks = (total + threads - 1) / threads;
    render_kernel<<<blocks, threads, 0, stream>>>(rays_o, rays_d, grid, scaling, offset, out, N);
}

// Round 3
// 489.383 us; speedup vs baseline: 1.4596x; 1.4596x over previous
//
#include <hip/hip_runtime.h>
#include <math.h>

#define RGRID 128
#define NSTEPS 128
#define DATA_DIM 28

__device__ __forceinline__ float fast_rcp(float x) { return __builtin_amdgcn_rcpf(x); }

// One wave (64 lanes) per ray: lane = s*8 + c, s = step-slot (0..7), c = corner.
// Each iteration renders 8 consecutive steps:
//   1) every lane loads its (step, corner) voxel's 28 channels (7x float4, all independent)
//   2) corner-reduce within 8-lane groups (shfl_xor 1,2,4)
//   3) per-step transform (a,b) = (1-alpha, alpha*c); affine scan over s (shfl_up 8,16,32)
//   4) broadcast composite from lane 63, fold into carried (T, rgb)
__global__ __launch_bounds__(256) void render_kernel(
    const float* __restrict__ rays_o,
    const float* __restrict__ rays_d,
    const float* __restrict__ grid,
    const float* __restrict__ scaling,
    const float* __restrict__ offset,
    float* __restrict__ out, int N)
{
    int tid = blockIdx.x * blockDim.x + threadIdx.x;
    int ray = tid >> 6;
    int lane = tid & 63;
    int s = lane >> 3;
    int c = lane & 7;
    if (ray >= N) return;

    float ox = rays_o[ray * 3 + 0], oy = rays_o[ray * 3 + 1], oz = rays_o[ray * 3 + 2];
    float rdx = rays_d[ray * 3 + 0], rdy = rays_d[ray * 3 + 1], rdz = rays_d[ray * 3 + 2];
    float sx = scaling[0], sy = scaling[1], sz = scaling[2];
    float fx = offset[0], fy = offset[1], fz = offset[2];

    // normalize direction
    float dn = rsqrtf(rdx * rdx + rdy * rdy + rdz * rdz);
    float dirx = rdx * dn, diry = rdy * dn, dirz = rdz * dn;

    float o0 = ox * sx + fx, o1 = oy * sy + fy, o2 = oz * sz + fz;
    float d0 = dirx * sx, d1 = diry * sy, d2 = dirz * sz;
    float delta_scale = rsqrtf(d0 * d0 + d1 * d1 + d2 * d2);

    float a0 = fabsf(d0) > 1e-9f ? d0 : 1e-9f;
    float a1 = fabsf(d1) > 1e-9f ? d1 : 1e-9f;
    float a2 = fabsf(d2) > 1e-9f ? d2 : 1e-9f;
    float i0 = 1.0f / a0, i1 = 1.0f / a1, i2 = 1.0f / a2;

    float t1x = (0.0f - o0) * i0, t2x = (1.0f - o0) * i0;
    float t1y = (0.0f - o1) * i1, t2y = (1.0f - o1) * i1;
    float t1z = (0.0f - o2) * i2, t2z = (1.0f - o2) * i2;
    float tmin = fmaxf(fmaxf(fminf(t1x, t2x), fminf(t1y, t2y)), fminf(t1z, t2z));
    tmin = fmaxf(tmin, 0.0f);
    float tmax = fminf(fminf(fmaxf(t1x, t2x), fmaxf(t1y, t2y)), fmaxf(t1z, t2z));
    bool valid = tmax > tmin;
    float dt = valid ? (tmax - tmin) * (1.0f / NSTEPS) : 0.0f;
    float sig_scale = dt * delta_scale;

    // SH basis (degree 2, 9 terms)
    const float C0 = 0.28209479177387814f;
    const float C1 = 0.4886025119029199f;
    float b0 = C0;
    float b1 = -C1 * diry;
    float b2 = C1 * dirz;
    float b3 = -C1 * dirx;
    float b4 = 1.0925484305920792f * dirx * diry;
    float b5 = -1.0925484305920792f * diry * dirz;
    float b6 = 0.31539156525252005f * (2.0f * dirz * dirz - dirx * dirx - diry * diry);
    float b7 = -1.0925484305920792f * dirx * dirz;
    float b8 = 0.5462742152960396f * (dirx * dirx - diry * diry);

    int cdx = (c >> 2) & 1, cdy = (c >> 1) & 1, cdz = c & 1;
    int laneoff = (cdx << 14) + (cdy << 7) + cdz;
    // FMA-form corner weights: w_c = fs*w + fb
    float fsx = cdx ? 1.0f : -1.0f, fbx = cdx ? 0.0f : 1.0f;
    float fsy = cdy ? 1.0f : -1.0f, fby = cdy ? 0.0f : 1.0f;
    float fsz = cdz ? 1.0f : -1.0f, fbz = cdz ? 0.0f : 1.0f;

    float T = 1.0f, accr = 0.0f, accg = 0.0f, accb = 0.0f;
    float soff = (float)s + 0.5f;

    for (int it = 0; it < NSTEPS / 8; it++) {
        float t = tmin + ((float)(it * 8) + soff) * dt;
        float px = o0 + t * d0, py = o1 + t * d1, pz = o2 + t * d2;

        float gx = px * (float)RGRID - 0.5f;
        float gy = py * (float)RGRID - 0.5f;
        float gz = pz * (float)RGRID - 0.5f;
        gx = fminf(fmaxf(gx, 0.0f), 126.9999f);
        gy = fminf(fmaxf(gy, 0.0f), 126.9999f);
        gz = fminf(fmaxf(gz, 0.0f), 126.9999f);

        float flx = floorf(gx), fly = floorf(gy), flz = floorf(gz);
        int ix = (int)flx, iy = (int)fly, iz = (int)flz;
        float wx = gx - flx, wy = gy - fly, wz = gz - flz;

        float wgt = (fsx * wx + fbx) * (fsy * wy + fby) * (fsz * wz + fbz);

        int vox = (ix << 14) + (iy << 7) + iz + laneoff;
        const float4* gp = (const float4*)(grid + (size_t)vox * DATA_DIM);
        float4 v0 = gp[0], v1 = gp[1], v2 = gp[2], v3 = gp[3], v4 = gp[4], v5 = gp[5], v6 = gp[6];

        // channels 0..8 red SH, 9..17 green, 18..26 blue, 27 sigma
        float vr = b0 * v0.x + b1 * v0.y + b2 * v0.z + b3 * v0.w
                 + b4 * v1.x + b5 * v1.y + b6 * v1.z + b7 * v1.w + b8 * v2.x;
        float vg = b0 * v2.y + b1 * v2.z + b2 * v2.w
                 + b3 * v3.x + b4 * v3.y + b5 * v3.z + b6 * v3.w
                 + b7 * v4.x + b8 * v4.y;
        float vb = b0 * v4.z + b1 * v4.w
                 + b2 * v5.x + b3 * v5.y + b4 * v5.z + b5 * v5.w
                 + b6 * v6.x + b7 * v6.y + b8 * v6.z;
        float vs = v6.w;

        vr *= wgt; vg *= wgt; vb *= wgt; vs *= wgt;

        // reduce over the 8 corner lanes (stays within each step's 8-lane group)
        #pragma unroll
        for (int m = 1; m < 8; m <<= 1) {
            vr += __shfl_xor(vr, m);
            vg += __shfl_xor(vg, m);
            vb += __shfl_xor(vb, m);
            vs += __shfl_xor(vs, m);
        }

        // per-step affine transform: state' = (T*a, rgb + T*b)
        float sigma = valid ? fmaxf(vs, 0.0f) : 0.0f;
        float alpha = 1.0f - __expf(-sigma * sig_scale);
        float av = 1.0f - alpha;
        float br = alpha * fast_rcp(1.0f + __expf(-vr));
        float bg = alpha * fast_rcp(1.0f + __expf(-vg));
        float bb = alpha * fast_rcp(1.0f + __expf(-vb));

        // inclusive affine scan over step-slots (stride 8,16,32 lanes)
        #pragma unroll
        for (int d = 8; d < 64; d <<= 1) {
            float pa  = __shfl_up(av, d);
            float pbr = __shfl_up(br, d);
            float pbg = __shfl_up(bg, d);
            float pbb = __shfl_up(bb, d);
            if (lane >= d) {
                br = pbr + pa * br;
                bg = pbg + pa * bg;
                bb = pbb + pa * bb;
                av = pa * av;
            }
        }

        // fold 8-step composite (lane 63 holds it) into carried state
        float ca  = __shfl(av, 63);
        float cbr = __shfl(br, 63);
        float cbg = __shfl(bg, 63);
        float cbb = __shfl(bb, 63);
        accr += T * cbr;
        accg += T * cbg;
        accb += T * cbb;
        T *= ca;
    }

    if (lane == 0) {
        out[ray * 3 + 0] = accr + T * 1.0f;  // BG = 1.0
        out[ray * 3 + 1] = accg + T * 1.0f;
        out[ray * 3 + 2] = accb + T * 1.0f;
    }
}

extern "C" void kernel_launch(void* const* d_in, const int* in_sizes, int n_in,
                              void* d_out, int out_size, void* d_ws, size_t ws_size,
                              hipStream_t stream) {
    const float* rays_o  = (const float*)d_in[0];
    const float* rays_d  = (const float*)d_in[1];
    const float* grid    = (const float*)d_in[2];
    const float* scaling = (const float*)d_in[3];
    const float* offset  = (const float*)d_in[4];
    float* out = (float*)d_out;
    int N = in_sizes[0] / 3;  // 32768 rays

    int threads = 256;                 // 4 waves/block = 4 rays/block
    long long total = (long long)N * 64;
    int blocks = (int)((total + threads - 1) / threads);
    render_kernel<<<blocks, threads, 0, stream>>>(rays_o, rays_d, grid, scaling, offset, out, N);
}